// Round 4
// baseline (4837.377 us; speedup 1.0000x reference)
//
#include <hip/hip_runtime.h>
#include <hip/hip_bf16.h>

// GRU-variant: B=64, T=512, D=L=1024.
// P layout: rows m = t*64+b, cols n: [0,1024)=gate_h x-part, [1024,2048)=gate_o
// x-part, [2048,3072)=qx. Recurrence: persistent kernel, fence-free sync via
// DIRECT-OBSERVATION release: producer (bg,cg) drains its h chunk to L3
// (sc0sc1 write-through), then stores flags[bg][cg]=t+1. Every consumer wave
// polls ALL 64 flags of its domain (lane l reads flags[bg][l]) and releases
// on the GLOBAL condition __all(f>=t+1) — same lockstep property as a single
// go-flag, but without the counter-RMW hop (64-way serialized at one L3 bank)
// and without the go-flag broadcast hop. Arrive-after-read (flag set after
// vmcnt-tied A-read + hstage barrier) keeps the double-buffered h race-free.
// Barriers are RAW s_barrier + lgkmcnt(0) (no vmcnt drain): P-prefetch and
// out-store latencies stay off the barrier chain.

typedef __attribute__((ext_vector_type(4))) int   int4v;
typedef __attribute__((ext_vector_type(4))) short short4v;
typedef __attribute__((ext_vector_type(8))) short bf16x8;
typedef __attribute__((ext_vector_type(4))) float f32x4;

union Pack16 { int4v i; short4v s[2]; };
union FragU  { bf16x8 v; short4v s[2]; int4v i; };

__device__ __forceinline__ short f2bf(float f) {
  union { float f; unsigned u; } v; v.f = f;
  unsigned r = v.u + 0x7fffu + ((v.u >> 16) & 1u);
  return (short)(r >> 16);
}
__device__ __forceinline__ float bf2f(short s) {
  union { unsigned u; float f; } v; v.u = ((unsigned)(unsigned short)s) << 16;
  return v.f;
}

// LDS-only barrier: order LDS ops, do NOT drain vmcnt (keeps in-flight
// global prefetch/stores off the chain).
#define LDS_BARRIER()                                         \
  do {                                                        \
    asm volatile("s_waitcnt lgkmcnt(0)" ::: "memory");        \
    __builtin_amdgcn_s_barrier();                             \
    asm volatile("" ::: "memory");                            \
  } while (0)

// ---------------- prep kernels ----------------

// x[b][t][k] -> xbf[(t*64+b)][k] (bf16)
__global__ __launch_bounds__(256) void cast_x_kernel(const float* __restrict__ xf,
                                                     short* __restrict__ xbf, int n4) {
  int i = blockIdx.x * 256 + threadIdx.x;
  if (i < n4) {
    float4 v = ((const float4*)xf)[i];
    short4v o;
    o.x = f2bf(v.x); o.y = f2bf(v.y); o.z = f2bf(v.z); o.w = f2bf(v.w);
    int r_in = i >> 8, c = i & 255;
    int b = r_in >> 9, t = r_in & 511;
    ((short4v*)xbf)[((t << 6) + b) * 256 + c] = o;
  }
}

// dst[n0+n][1024-k] = f2bf(src[k0+k][n0+n]); src ld given. 64x64 tiles.
__global__ __launch_bounds__(256) void transpose_cast(const float* __restrict__ src,
                                                      long ld, short* __restrict__ dst) {
  __shared__ float tile[64][65];
  const int n0 = blockIdx.x << 6, k0 = blockIdx.y << 6;
  const int c = threadIdx.x & 63, rr = threadIdx.x >> 6;
#pragma unroll 4
  for (int i = 0; i < 16; ++i)
    tile[i * 4 + rr][c] = src[(long)(k0 + i * 4 + rr) * ld + n0 + c];
  __syncthreads();
#pragma unroll 4
  for (int i = 0; i < 16; ++i)
    dst[(long)(n0 + i * 4 + rr) * 1024 + k0 + c] = f2bf(tile[c][i * 4 + rr]);
}

// biasP = [wb | wxb]; h0 -> bf16 buffer 0
__global__ __launch_bounds__(256) void prep_misc(const float* __restrict__ wb,
                                                 const float* __restrict__ wxb,
                                                 const float* __restrict__ h0,
                                                 float* __restrict__ biasP,
                                                 short* __restrict__ hbf0) {
  int i = blockIdx.x * 256 + threadIdx.x;
  if (i < 65536) {
    hbf0[i] = f2bf(h0[i]);
  } else {
    int n = i - 65536;
    if (n < 3072) biasP[n] = (n < 2048) ? wb[n] : wxb[n - 2048];
  }
}

// ---------------- phase 1: P-GEMM ----------------
__global__ __launch_bounds__(256) void pgemm_kernel(const short* __restrict__ A,
                                                    const short* __restrict__ Bt,
                                                    const float* __restrict__ biasP,
                                                    short* __restrict__ P) {
  __shared__ short As[128][36];
  __shared__ short Bs[128][36];
  const int tid = threadIdx.x;
  const int m0 = blockIdx.y << 7;
  const int n0 = blockIdx.x << 7;
  const int w = tid >> 6, lane = tid & 63;
  const int wm = w >> 1, wn = w & 1;
  const int q = lane >> 4, r = lane & 15;
  const int srow = tid >> 1, shalf = tid & 1;

  const f32x4 zero = {0.f, 0.f, 0.f, 0.f};
  f32x4 acc[4][4];
#pragma unroll
  for (int a = 0; a < 4; ++a)
#pragma unroll
    for (int b = 0; b < 4; ++b) acc[a][b] = zero;

  const short* gA = A + (long)(m0 + srow) * 1024 + shalf * 16;
  const short* gB = Bt + (long)(n0 + srow) * 1024 + shalf * 16;

  for (int kk = 0; kk < 1024; kk += 32) {
    Pack16 a0, a1, b0, b1;
    a0.i = *(const int4v*)(gA + kk);
    a1.i = *(const int4v*)(gA + kk + 8);
    b0.i = *(const int4v*)(gB + kk);
    b1.i = *(const int4v*)(gB + kk + 8);
    short* wA = &As[srow][shalf * 16];
    *(short4v*)(wA)      = a0.s[0];
    *(short4v*)(wA + 4)  = a0.s[1];
    *(short4v*)(wA + 8)  = a1.s[0];
    *(short4v*)(wA + 12) = a1.s[1];
    short* wB = &Bs[srow][shalf * 16];
    *(short4v*)(wB)      = b0.s[0];
    *(short4v*)(wB + 4)  = b0.s[1];
    *(short4v*)(wB + 8)  = b1.s[0];
    *(short4v*)(wB + 12) = b1.s[1];
    __syncthreads();

    FragU af[4], bfv[4];
#pragma unroll
    for (int mi = 0; mi < 4; ++mi) {
      const short* pa = &As[wm * 64 + mi * 16 + r][q * 8];
      af[mi].s[0] = *(const short4v*)pa;
      af[mi].s[1] = *(const short4v*)(pa + 4);
    }
#pragma unroll
    for (int ni = 0; ni < 4; ++ni) {
      const short* pb = &Bs[wn * 64 + ni * 16 + r][q * 8];
      bfv[ni].s[0] = *(const short4v*)pb;
      bfv[ni].s[1] = *(const short4v*)(pb + 4);
    }
#pragma unroll
    for (int mi = 0; mi < 4; ++mi)
#pragma unroll
      for (int ni = 0; ni < 4; ++ni)
        acc[mi][ni] = __builtin_amdgcn_mfma_f32_16x16x32_bf16(af[mi].v, bfv[ni].v,
                                                              acc[mi][ni], 0, 0, 0);
    __syncthreads();
  }

#pragma unroll
  for (int ni = 0; ni < 4; ++ni) {
    int gn = n0 + wn * 64 + ni * 16 + r;
    float bias = biasP[gn];
#pragma unroll
    for (int mi = 0; mi < 4; ++mi) {
      int gm = m0 + wm * 64 + mi * 16 + q * 4;
#pragma unroll
      for (int i = 0; i < 4; ++i)
        P[(long)(gm + i) * 3072 + gn] = f2bf(acc[mi][ni][i] + bias);
    }
  }
}

// ---------------- phase 2: persistent recurrence ----------------
// Grid 256 = 4 domains (bg, 16 batches) x 64 col-blocks (cg, 16 j).
// Wave w owns K-slice [w*256, +256). RT B-frags register-resident.
// Sync: per-producer flags, global all-64 release condition per wave.
__global__ __launch_bounds__(256, 1) void recur_kernel(const short* __restrict__ RT,
                                                       const short* __restrict__ P,
                                                       const float* __restrict__ whb,
                                                       const float* __restrict__ h0,
                                                       short* __restrict__ hbuf,
                                                       float* __restrict__ out,
                                                       unsigned* __restrict__ sync) {
  __shared__ float Lred[4][3][256];
  __shared__ unsigned long long hstage_u[32];
  short* hstage = (short*)hstage_u;

  const int tid = threadIdx.x;
  const int bid = blockIdx.x;
  const int cg = bid & 63, bg = bid >> 6;
  const int w = tid >> 6, lane = tid & 63;
  const int q = lane >> 4, r = lane & 15;
  const int ks = w << 8;
  const f32x4 zero = {0.f, 0.f, 0.f, 0.f};

  // B-frags: 3 n-tiles (j, 1024+j, 2048+j) x 8 k-iters, register/AGPR resident.
  FragU Bf[3][8];
#pragma unroll
  for (int nt = 0; nt < 3; ++nt)
#pragma unroll
    for (int ki = 0; ki < 8; ++ki) {
      const short* p = RT + (long)(nt * 1024 + cg * 16 + r) * 1024 + ks + ki * 32 + q * 8;
      Pack16 t16; t16.i = *(const int4v*)p;
      Bf[nt][ki].s[0] = t16.s[0]; Bf[nt][ki].s[1] = t16.s[1];
    }

  const int bl = tid >> 4, jl = tid & 15;
  float hp = h0[(long)(bg * 16 + bl) * 1024 + cg * 16 + jl];
  const float whbr = whb[cg * 16 + jl];
  const short* Pbase = P + (long)(bg * 16 + bl) * 3072 + cg * 16 + jl;
  short p0n = Pbase[0], p1n = Pbase[1024], p2n = Pbase[2048];  // t=0 prefetch
  const long outbase = ((long)(bg * 16 + bl) * 512) * 1024 + cg * 16 + jl;

  // flags: domain bg owns words [bg*128, bg*128+64) (512B stride between
  // domains). Producer (bg,cg) writes word cg; every wave's lane l polls
  // word l -> one wave-poll = 2 x 128B line reads, global all-64 condition.
  unsigned* myflag = sync + (bg << 7) + cg;
  const unsigned* pollp = sync + (bg << 7) + lane;

  for (int t = 0; t < 512; ++t) {
    const short* hcur = hbuf + (t & 1) * 65536;
    short* hnext = hbuf + ((t + 1) & 1) * 65536;

    // A-frags: 8 x 16B coherent loads (bypass L1/L2, read L3) + tied waitcnt.
    const short* aptr = hcur + (bg * 16 + r) * 1024 + ks + q * 8;
    FragU Af[8];
    asm volatile(
        "global_load_dwordx4 %0, %8, off sc0 sc1\n\t"
        "global_load_dwordx4 %1, %8, off offset:64 sc0 sc1\n\t"
        "global_load_dwordx4 %2, %8, off offset:128 sc0 sc1\n\t"
        "global_load_dwordx4 %3, %8, off offset:192 sc0 sc1\n\t"
        "global_load_dwordx4 %4, %8, off offset:256 sc0 sc1\n\t"
        "global_load_dwordx4 %5, %8, off offset:320 sc0 sc1\n\t"
        "global_load_dwordx4 %6, %8, off offset:384 sc0 sc1\n\t"
        "global_load_dwordx4 %7, %8, off offset:448 sc0 sc1\n\t"
        "s_waitcnt vmcnt(0)"
        : "=&v"(Af[0].i), "=&v"(Af[1].i), "=&v"(Af[2].i), "=&v"(Af[3].i),
          "=&v"(Af[4].i), "=&v"(Af[5].i), "=&v"(Af[6].i), "=&v"(Af[7].i)
        : "v"(aptr)
        : "memory");

    // capture this step's P, prefetch t+1 (plain cached loads; with raw
    // barriers they have the FULL step to land — next drain point is the
    // t+1 A-load vmcnt(0))
    short c0 = p0n, c1 = p1n, c2 = p2n;
    if (t < 511) {
      const short* Pn = Pbase + (long)(t + 1) * 196608;
      p0n = Pn[0]; p1n = Pn[1024]; p2n = Pn[2048];
    }

    f32x4 acc0 = zero, acc1 = zero, acc2 = zero;
#pragma unroll
    for (int ki = 0; ki < 8; ++ki) {
      acc0 = __builtin_amdgcn_mfma_f32_16x16x32_bf16(Af[ki].v, Bf[0][ki].v, acc0, 0, 0, 0);
      acc1 = __builtin_amdgcn_mfma_f32_16x16x32_bf16(Af[ki].v, Bf[1][ki].v, acc1, 0, 0, 0);
      acc2 = __builtin_amdgcn_mfma_f32_16x16x32_bf16(Af[ki].v, Bf[2][ki].v, acc2, 0, 0, 0);
    }

    // cross-wave K reduction. C/D layout: col=r, row=q*4+i.
#pragma unroll
    for (int i = 0; i < 4; ++i) {
      Lred[w][0][(q * 4 + i) * 16 + r] = acc0[i];
      Lred[w][1][(q * 4 + i) * 16 + r] = acc1[i];
      Lred[w][2][(q * 4 + i) * 16 + r] = acc2[i];
    }
    LDS_BARRIER();

    float g0 = Lred[0][0][tid] + Lred[1][0][tid] + Lred[2][0][tid] + Lred[3][0][tid];
    float g1 = Lred[0][1][tid] + Lred[1][1][tid] + Lred[2][1][tid] + Lred[3][1][tid];
    float g2 = Lred[0][2][tid] + Lred[1][2][tid] + Lred[2][2][tid] + Lred[3][2][tid];

    float gh = 1.f / (1.f + __expf(-(bf2f(c0) + g0)));
    float go = 1.f / (1.f + __expf(-(bf2f(c1) + g1)));
    float mem = bf2f(c2) + gh * (g2 + whbr);
    float e = __expf(2.f * mem);
    float th = 1.f - 2.f / (e + 1.f);
    float hn = go * hp + (1.f - go) * th;
    hp = hn;
    out[outbase + (long)t * 1024] = hn;
    hstage[tid] = f2bf(hn);
    LDS_BARRIER();  // hstage visible to wave 0 (also: all Lred reads done)

    if (tid < 64) {  // wave 0: write-through h to L3, drain, publish own flag
      int row = bg * 16 + (tid >> 2);
      unsigned long long* hp64 = (unsigned long long*)(hnext + row * 1024 + cg * 16 + (tid & 3) * 4);
      __hip_atomic_store(hp64, hstage_u[tid], __ATOMIC_RELAXED, __HIP_MEMORY_SCOPE_AGENT);
      asm volatile("s_waitcnt vmcnt(0)" ::: "memory");
      if (tid == 0)
        __hip_atomic_store(myflag, (unsigned)(t + 1), __ATOMIC_RELAXED,
                           __HIP_MEMORY_SCOPE_AGENT);
    }

    // every wave polls all 64 producer flags; release is the GLOBAL all-64
    // condition (same lockstep as a go-flag, one hop earlier).
    for (;;) {
      unsigned f = __hip_atomic_load(pollp, __ATOMIC_RELAXED, __HIP_MEMORY_SCOPE_AGENT);
      if (__all((int)(f >= (unsigned)(t + 1)))) break;
      __builtin_amdgcn_s_sleep(1);
    }
  }
}

// ---------------- launch ----------------

extern "C" void kernel_launch(void* const* d_in, const int* in_sizes, int n_in,
                              void* d_out, int out_size, void* d_ws, size_t ws_size,
                              hipStream_t stream) {
  const float* x   = (const float*)d_in[0];  // [64][512][1024]
  const float* h0  = (const float*)d_in[1];  // [64][1024]
  const float* wW  = (const float*)d_in[2];  // [2048][2048]
  const float* wb  = (const float*)d_in[3];  // [2048]
  const float* wxW = (const float*)d_in[4];  // [1024][1024]
  const float* wxb = (const float*)d_in[5];  // [1024]
  const float* whW = (const float*)d_in[6];  // [1024][1024]
  const float* whb = (const float*)d_in[7];  // [1024]
  float* out = (float*)d_out;                // [64][512][1024]

  char* ws = (char*)d_ws;
  short*    P     = (short*)(ws);               // 201326592
  short*    xbf   = (short*)(ws + 201326592);   // 67108864
  short*    XwT   = (short*)(ws + 268435456);   // 6291456
  short*    RT    = (short*)(ws + 274726912);   // 6291456
  float*    biasP = (float*)(ws + 281018368);   // 12288
  short*    hbf   = (short*)(ws + 281030656);   // 262144 (2 buffers)
  unsigned* sync  = (unsigned*)(ws + 281292800);// 2048 (4 domains x 128 words)

  hipMemsetAsync(sync, 0, 2048, stream);
  cast_x_kernel<<<dim3(32768), dim3(256), 0, stream>>>(x, xbf, 8388608);
  transpose_cast<<<dim3(32, 16), dim3(256), 0, stream>>>(wW, 2048, XwT);
  transpose_cast<<<dim3(16, 16), dim3(256), 0, stream>>>(wxW, 1024, XwT + 2048 * 1024);
  transpose_cast<<<dim3(32, 16), dim3(256), 0, stream>>>(wW + 1024 * 2048, 2048, RT);
  transpose_cast<<<dim3(16, 16), dim3(256), 0, stream>>>(whW, 1024, RT + 2048 * 1024);
  prep_misc<<<dim3(268), dim3(256), 0, stream>>>(wb, wxb, h0, biasP, hbf);
  pgemm_kernel<<<dim3(24, 256), dim3(256), 0, stream>>>(xbf, XwT, biasP, P);
  recur_kernel<<<dim3(256), dim3(256), 0, stream>>>(RT, P, whb, h0, hbf, out, sync);
}

// Round 5
// 2489.856 us; speedup vs baseline: 1.9428x; 1.9428x over previous
//
#include <hip/hip_runtime.h>
#include <hip/hip_bf16.h>

// GRU-variant: B=64, T=512, D=L=1024.
// P layout: rows m = t*64+b, cols n: [0,1024)=gate_h x-part, [1024,2048)=gate_o
// x-part, [2048,3072)=qx. Recurrence: persistent kernel, fence-free sync:
// relaxed agent atomics + sc0sc1 write-through h exchange; hot per-domain
// counter (threshold 64*(t+1), never reset) + go-flag. Sync-line discipline
// (learned r1/r2/r4): never let many waves poll a line that many blocks
// write. Counter: 64 writers, 0 pollers. Go-flag: 1 writer, and (new) only
// wave 0 of each block polls — waves 1-3 released via raw s_barrier. Raw
// barriers (lgkmcnt only, no vmcnt drain) keep P-prefetch/out-stores off the
// chain. Arrive-after-read makes double-buffered h race-free.

typedef __attribute__((ext_vector_type(4))) int   int4v;
typedef __attribute__((ext_vector_type(4))) short short4v;
typedef __attribute__((ext_vector_type(8))) short bf16x8;
typedef __attribute__((ext_vector_type(4))) float f32x4;

union Pack16 { int4v i; short4v s[2]; };
union FragU  { bf16x8 v; short4v s[2]; int4v i; };

__device__ __forceinline__ short f2bf(float f) {
  union { float f; unsigned u; } v; v.f = f;
  unsigned r = v.u + 0x7fffu + ((v.u >> 16) & 1u);
  return (short)(r >> 16);
}
__device__ __forceinline__ float bf2f(short s) {
  union { unsigned u; float f; } v; v.u = ((unsigned)(unsigned short)s) << 16;
  return v.f;
}

// LDS-only barrier: order LDS ops, do NOT drain vmcnt.
#define LDS_BARRIER()                                         \
  do {                                                        \
    asm volatile("s_waitcnt lgkmcnt(0)" ::: "memory");        \
    __builtin_amdgcn_s_barrier();                             \
    asm volatile("" ::: "memory");                            \
  } while (0)

// async global->LDS, 16B per lane. LDS dest must be wave-uniform base;
// lane l lands at l*16 bytes past it.
__device__ __forceinline__ void gload_lds16(const short* g, short* l) {
  __builtin_amdgcn_global_load_lds(
      (const __attribute__((address_space(1))) void*)g,
      (__attribute__((address_space(3))) void*)l, 16, 0, 0);
}

// ---------------- prep kernels ----------------

// x[b][t][k] -> xbf[(t*64+b)][k] (bf16)
__global__ __launch_bounds__(256) void cast_x_kernel(const float* __restrict__ xf,
                                                     short* __restrict__ xbf, int n4) {
  int i = blockIdx.x * 256 + threadIdx.x;
  if (i < n4) {
    float4 v = ((const float4*)xf)[i];
    short4v o;
    o.x = f2bf(v.x); o.y = f2bf(v.y); o.z = f2bf(v.z); o.w = f2bf(v.w);
    int r_in = i >> 8, c = i & 255;
    int b = r_in >> 9, t = r_in & 511;
    ((short4v*)xbf)[((t << 6) + b) * 256 + c] = o;
  }
}

// dst[n0+n][1024-k] = f2bf(src[k0+k][n0+n]); src ld given. 64x64 tiles.
__global__ __launch_bounds__(256) void transpose_cast(const float* __restrict__ src,
                                                      long ld, short* __restrict__ dst) {
  __shared__ float tile[64][65];
  const int n0 = blockIdx.x << 6, k0 = blockIdx.y << 6;
  const int c = threadIdx.x & 63, rr = threadIdx.x >> 6;
#pragma unroll 4
  for (int i = 0; i < 16; ++i)
    tile[i * 4 + rr][c] = src[(long)(k0 + i * 4 + rr) * ld + n0 + c];
  __syncthreads();
#pragma unroll 4
  for (int i = 0; i < 16; ++i)
    dst[(long)(n0 + i * 4 + rr) * 1024 + k0 + c] = f2bf(tile[c][i * 4 + rr]);
}

// biasP = [wb | wxb]; h0 -> bf16 buffer 0
__global__ __launch_bounds__(256) void prep_misc(const float* __restrict__ wb,
                                                 const float* __restrict__ wxb,
                                                 const float* __restrict__ h0,
                                                 float* __restrict__ biasP,
                                                 short* __restrict__ hbf0) {
  int i = blockIdx.x * 256 + threadIdx.x;
  if (i < 65536) {
    hbf0[i] = f2bf(h0[i]);
  } else {
    int n = i - 65536;
    if (n < 3072) biasP[n] = (n < 2048) ? wb[n] : wxb[n - 2048];
  }
}

// ---------------- phase 1: P-GEMM (m97 structure) ----------------
// BM=BN=128, BK=32, linear LDS [128][32], global_load_lds width-16 staging:
// wave w fills rows [w*32,+32) via 2 insts (16 rows each); lane l -> row
// w*32+i*16+(l>>2), 16B chunk (l&3). Frags: single ds_read_b128 each.
__global__ __launch_bounds__(256) void pgemm_kernel(const short* __restrict__ A,
                                                    const short* __restrict__ Bt,
                                                    const float* __restrict__ biasP,
                                                    short* __restrict__ P) {
  __shared__ short As[128][32];
  __shared__ short Bs[128][32];
  const int tid = threadIdx.x;
  const int m0 = blockIdx.y << 7;
  const int n0 = blockIdx.x << 7;
  const int w = tid >> 6, lane = tid & 63;
  const int wm = w >> 1, wn = w & 1;
  const int q = lane >> 4, r = lane & 15;

  const int srow = (w << 5) + (lane >> 2);
  const int scol = (lane & 3) * 8;
  const short* gA0 = A  + (long)(m0 + srow) * 1024 + scol;
  const short* gA1 = gA0 + 16 * 1024;
  const short* gB0 = Bt + (long)(n0 + srow) * 1024 + scol;
  const short* gB1 = gB0 + 16 * 1024;
  short* lA0 = &As[(w << 5)][0];        // wave-uniform LDS bases
  short* lA1 = &As[(w << 5) + 16][0];
  short* lB0 = &Bs[(w << 5)][0];
  short* lB1 = &Bs[(w << 5) + 16][0];

  const f32x4 zero = {0.f, 0.f, 0.f, 0.f};
  f32x4 acc[4][4];
#pragma unroll
  for (int a = 0; a < 4; ++a)
#pragma unroll
    for (int b = 0; b < 4; ++b) acc[a][b] = zero;

  for (int kk = 0; kk < 1024; kk += 32) {
    gload_lds16(gA0 + kk, lA0);
    gload_lds16(gA1 + kk, lA1);
    gload_lds16(gB0 + kk, lB0);
    gload_lds16(gB1 + kk, lB1);
    __syncthreads();  // vmcnt(0) drain: LDS tiles ready

    FragU af[4], bfv[4];
#pragma unroll
    for (int mi = 0; mi < 4; ++mi)
      af[mi].i = *(const int4v*)&As[wm * 64 + mi * 16 + r][q * 8];
#pragma unroll
    for (int ni = 0; ni < 4; ++ni)
      bfv[ni].i = *(const int4v*)&Bs[wn * 64 + ni * 16 + r][q * 8];
#pragma unroll
    for (int mi = 0; mi < 4; ++mi)
#pragma unroll
      for (int ni = 0; ni < 4; ++ni)
        acc[mi][ni] = __builtin_amdgcn_mfma_f32_16x16x32_bf16(af[mi].v, bfv[ni].v,
                                                              acc[mi][ni], 0, 0, 0);
    __syncthreads();  // LDS reads done before next stage overwrites
  }

#pragma unroll
  for (int ni = 0; ni < 4; ++ni) {
    int gn = n0 + wn * 64 + ni * 16 + r;
    float bias = biasP[gn];
#pragma unroll
    for (int mi = 0; mi < 4; ++mi) {
      int gm = m0 + wm * 64 + mi * 16 + q * 4;
#pragma unroll
      for (int i = 0; i < 4; ++i)
        P[(long)(gm + i) * 3072 + gn] = f2bf(acc[mi][ni][i] + bias);
    }
  }
}

// ---------------- phase 2: persistent recurrence ----------------
// Grid 256 = 4 domains (bg, 16 batches) x 64 col-blocks (cg, 16 j).
// Wave w owns K-slice [w*256, +256). RT B-frags register-resident.
// Sync: hot counter + go-flag; wave-0-only polling, barrier release.
__global__ __launch_bounds__(256, 1) void recur_kernel(const short* __restrict__ RT,
                                                       const short* __restrict__ P,
                                                       const float* __restrict__ whb,
                                                       const float* __restrict__ h0,
                                                       short* __restrict__ hbuf,
                                                       float* __restrict__ out,
                                                       unsigned* __restrict__ sync) {
  __shared__ float Lred[4][3][256];
  __shared__ unsigned long long hstage_u[32];
  short* hstage = (short*)hstage_u;

  const int tid = threadIdx.x;
  const int bid = blockIdx.x;
  const int cg = bid & 63, bg = bid >> 6;
  const int w = tid >> 6, lane = tid & 63;
  const int q = lane >> 4, r = lane & 15;
  const int ks = w << 8;
  const f32x4 zero = {0.f, 0.f, 0.f, 0.f};

  // B-frags: 3 n-tiles (j, 1024+j, 2048+j) x 8 k-iters, register/AGPR resident.
  FragU Bf[3][8];
#pragma unroll
  for (int nt = 0; nt < 3; ++nt)
#pragma unroll
    for (int ki = 0; ki < 8; ++ki) {
      const short* p = RT + (long)(nt * 1024 + cg * 16 + r) * 1024 + ks + ki * 32 + q * 8;
      Pack16 t16; t16.i = *(const int4v*)p;
      Bf[nt][ki].s[0] = t16.s[0]; Bf[nt][ki].s[1] = t16.s[1];
    }

  const int bl = tid >> 4, jl = tid & 15;
  float hp = h0[(long)(bg * 16 + bl) * 1024 + cg * 16 + jl];
  const float whbr = whb[cg * 16 + jl];
  const short* Pbase = P + (long)(bg * 16 + bl) * 3072 + cg * 16 + jl;
  short p0n = Pbase[0], p1n = Pbase[1024], p2n = Pbase[2048];  // t=0 prefetch
  const long outbase = ((long)(bg * 16 + bl) * 512) * 1024 + cg * 16 + jl;

  unsigned* ctr = sync + bg * 32;        // hot counter line (never reset)
  unsigned* gf  = sync + 128 + bg * 32;  // go-flag, own 128B line

  for (int t = 0; t < 512; ++t) {
    const short* hcur = hbuf + (t & 1) * 65536;
    short* hnext = hbuf + ((t + 1) & 1) * 65536;

    // A-frags: 8 x 16B coherent loads (bypass L1/L2, read L3) + tied waitcnt.
    const short* aptr = hcur + (bg * 16 + r) * 1024 + ks + q * 8;
    FragU Af[8];
    asm volatile(
        "global_load_dwordx4 %0, %8, off sc0 sc1\n\t"
        "global_load_dwordx4 %1, %8, off offset:64 sc0 sc1\n\t"
        "global_load_dwordx4 %2, %8, off offset:128 sc0 sc1\n\t"
        "global_load_dwordx4 %3, %8, off offset:192 sc0 sc1\n\t"
        "global_load_dwordx4 %4, %8, off offset:256 sc0 sc1\n\t"
        "global_load_dwordx4 %5, %8, off offset:320 sc0 sc1\n\t"
        "global_load_dwordx4 %6, %8, off offset:384 sc0 sc1\n\t"
        "global_load_dwordx4 %7, %8, off offset:448 sc0 sc1\n\t"
        "s_waitcnt vmcnt(0)"
        : "=&v"(Af[0].i), "=&v"(Af[1].i), "=&v"(Af[2].i), "=&v"(Af[3].i),
          "=&v"(Af[4].i), "=&v"(Af[5].i), "=&v"(Af[6].i), "=&v"(Af[7].i)
        : "v"(aptr)
        : "memory");

    // capture this step's P, prefetch t+1 (plain cached loads; with raw
    // barriers they have the FULL step to land — next drain point is the
    // t+1 A-load vmcnt(0))
    short c0 = p0n, c1 = p1n, c2 = p2n;
    if (t < 511) {
      const short* Pn = Pbase + (long)(t + 1) * 196608;
      p0n = Pn[0]; p1n = Pn[1024]; p2n = Pn[2048];
    }

    f32x4 acc0 = zero, acc1 = zero, acc2 = zero;
#pragma unroll
    for (int ki = 0; ki < 8; ++ki) {
      acc0 = __builtin_amdgcn_mfma_f32_16x16x32_bf16(Af[ki].v, Bf[0][ki].v, acc0, 0, 0, 0);
      acc1 = __builtin_amdgcn_mfma_f32_16x16x32_bf16(Af[ki].v, Bf[1][ki].v, acc1, 0, 0, 0);
      acc2 = __builtin_amdgcn_mfma_f32_16x16x32_bf16(Af[ki].v, Bf[2][ki].v, acc2, 0, 0, 0);
    }

    // cross-wave K reduction. C/D layout: col=r, row=q*4+i.
#pragma unroll
    for (int i = 0; i < 4; ++i) {
      Lred[w][0][(q * 4 + i) * 16 + r] = acc0[i];
      Lred[w][1][(q * 4 + i) * 16 + r] = acc1[i];
      Lred[w][2][(q * 4 + i) * 16 + r] = acc2[i];
    }
    LDS_BARRIER();

    float g0 = Lred[0][0][tid] + Lred[1][0][tid] + Lred[2][0][tid] + Lred[3][0][tid];
    float g1 = Lred[0][1][tid] + Lred[1][1][tid] + Lred[2][1][tid] + Lred[3][1][tid];
    float g2 = Lred[0][2][tid] + Lred[1][2][tid] + Lred[2][2][tid] + Lred[3][2][tid];

    float gh = 1.f / (1.f + __expf(-(bf2f(c0) + g0)));
    float go = 1.f / (1.f + __expf(-(bf2f(c1) + g1)));
    float mem = bf2f(c2) + gh * (g2 + whbr);
    float e = __expf(2.f * mem);
    float th = 1.f - 2.f / (e + 1.f);
    float hn = go * hp + (1.f - go) * th;
    hp = hn;
    out[outbase + (long)t * 1024] = hn;
    hstage[tid] = f2bf(hn);
    LDS_BARRIER();  // hstage visible to wave 0 (also: all Lred reads done)

    if (tid < 64) {  // wave 0: write-through h to L3, drain, arrive
      int row = bg * 16 + (tid >> 2);
      unsigned long long* hp64 = (unsigned long long*)(hnext + row * 1024 + cg * 16 + (tid & 3) * 4);
      __hip_atomic_store(hp64, hstage_u[tid], __ATOMIC_RELAXED, __HIP_MEMORY_SCOPE_AGENT);
      asm volatile("s_waitcnt vmcnt(0)" ::: "memory");
      if (tid == 0) {
        unsigned old = __hip_atomic_fetch_add(ctr, 1u, __ATOMIC_RELAXED,
                                              __HIP_MEMORY_SCOPE_AGENT);
        if (old == 64u * (unsigned)(t + 1) - 1u)
          __hip_atomic_store(gf, (unsigned)(t + 1), __ATOMIC_RELAXED,
                             __HIP_MEMORY_SCOPE_AGENT);
      }
      // wave 0 alone polls the go-flag (64 pollers/line instead of 256:
      // the release store doesn't queue behind a poll flood)
      while (__hip_atomic_load(gf, __ATOMIC_RELAXED, __HIP_MEMORY_SCOPE_AGENT) <
             (unsigned)(t + 1))
        __builtin_amdgcn_s_sleep(1);
    }
    // waves 1-3 wait here; wave 0 joins after detecting the go-flag
    LDS_BARRIER();
  }
}

// ---------------- launch ----------------

extern "C" void kernel_launch(void* const* d_in, const int* in_sizes, int n_in,
                              void* d_out, int out_size, void* d_ws, size_t ws_size,
                              hipStream_t stream) {
  const float* x   = (const float*)d_in[0];  // [64][512][1024]
  const float* h0  = (const float*)d_in[1];  // [64][1024]
  const float* wW  = (const float*)d_in[2];  // [2048][2048]
  const float* wb  = (const float*)d_in[3];  // [2048]
  const float* wxW = (const float*)d_in[4];  // [1024][1024]
  const float* wxb = (const float*)d_in[5];  // [1024]
  const float* whW = (const float*)d_in[6];  // [1024][1024]
  const float* whb = (const float*)d_in[7];  // [1024]
  float* out = (float*)d_out;                // [64][512][1024]

  char* ws = (char*)d_ws;
  short*    P     = (short*)(ws);               // 201326592
  short*    xbf   = (short*)(ws + 201326592);   // 67108864
  short*    XwT   = (short*)(ws + 268435456);   // 6291456
  short*    RT    = (short*)(ws + 274726912);   // 6291456
  float*    biasP = (float*)(ws + 281018368);   // 12288
  short*    hbf   = (short*)(ws + 281030656);   // 262144 (2 buffers)
  unsigned* sync  = (unsigned*)(ws + 281292800);// 1024 (4 ctr lines + 4 flag lines)

  hipMemsetAsync(sync, 0, 1024, stream);
  cast_x_kernel<<<dim3(32768), dim3(256), 0, stream>>>(x, xbf, 8388608);
  transpose_cast<<<dim3(32, 16), dim3(256), 0, stream>>>(wW, 2048, XwT);
  transpose_cast<<<dim3(16, 16), dim3(256), 0, stream>>>(wxW, 1024, XwT + 2048 * 1024);
  transpose_cast<<<dim3(32, 16), dim3(256), 0, stream>>>(wW + 1024 * 2048, 2048, RT);
  transpose_cast<<<dim3(16, 16), dim3(256), 0, stream>>>(whW, 1024, RT + 2048 * 1024);
  prep_misc<<<dim3(268), dim3(256), 0, stream>>>(wb, wxb, h0, biasP, hbf);
  pgemm_kernel<<<dim3(24, 256), dim3(256), 0, stream>>>(xbf, XwT, biasP, P);
  recur_kernel<<<dim3(256), dim3(256), 0, stream>>>(RT, P, whb, h0, hbf, out, sync);
}